// Round 6
// baseline (1290.521 us; speedup 1.0000x reference)
//
#include <hip/hip_runtime.h>
#include <math.h>

// ---------------------------------------------------------------------------
// CSAttention forward, MI355X. GEMMs via split-bf16 (hi/lo) 3-MFMA emulation:
//   A*B ~= Ah*Bh + Al*Bh + Ah*Bl   (fp32 accumulate, ~16 mantissa bits)
// Layout: token maps (b, h*64+w, c) row-major, C=256, B=16.
// Ladder (gemmf µs): R5 reg+pad 70 | R6 gload 79 | R7 dbuf 73 | R8 reg-unpad 89
//   | R9 gload+swz 80 (conflicts->0) | R10 reg+swz manual-sched 78 (best total
//   1281.8 via chunk-outer loop reorder).
// R11: (a) R5's exact loop shape (stage inline at top, ROLLED loop, 2 syncs --
//      compiler pipelines best, min register lifetime) + R9 swizzled layout
//      (conflict-free both sides, 32 KB LDS);
//      (b) bijective XCD swizzle (1D grids): col/mat blocks sharing an A-tile
//      co-locate on one XCD -> A re-reads L2-local;
//      (c) dispatch cuts: 3 weight-splits -> 1; edge_combine+avg_mlp -> fused
//      edge_sel (LDS edge tile, zero halo == reference skip semantics).
// ---------------------------------------------------------------------------

#define CHUNK_B 4
#define CHUNK_TOK (CHUNK_B * 4096)   // 16384 tokens per chunk
#define KS 32                        // LDS k-slice width (elements), 64B rows

typedef __attribute__((ext_vector_type(8))) short short8;
typedef __attribute__((ext_vector_type(8))) unsigned short ushort8;
typedef __attribute__((ext_vector_type(4))) float f32x4;

__device__ __forceinline__ ushort f2bf(float f) {
    union { float f; unsigned u; } v; v.f = f;
    unsigned r = v.u + 0x7fff + ((v.u >> 16) & 1);
    return (ushort)(r >> 16);
}
__device__ __forceinline__ float bf2f(ushort h) {
    union { unsigned u; float f; } v; v.u = ((unsigned)h) << 16; return v.f;
}
__device__ __forceinline__ void split2(float v, ushort& h, ushort& l) {
    h = f2bf(v);
    l = f2bf(v - bf2f(h));
}

// ---------------- fused weight pre-split (one dispatch) ---------------------
// Wt layout (ushort planes): [0,12*65536) attn_w k-major; [12*65536,15*65536)
// ax_w k-major; [15*65536, +131072) sq_w n-major. Total 1,114,112.
__global__ __launch_bounds__(256) void split_w_all(
    const float* __restrict__ AW, const float* __restrict__ XW,
    const float* __restrict__ SW, ushort* __restrict__ Th, ushort* __restrict__ Tl)
{
    const int idx = blockIdx.x * 256 + threadIdx.x;
    if (idx >= 1114112) return;
    float v;
    if (idx < 786432) {
        const int mat = idx >> 16, r = idx & 65535;
        const int n = r >> 8, k = r & 255;
        v = AW[(size_t)mat * 65536 + k * 256 + n];
    } else if (idx < 983040) {
        const int j = idx - 786432;
        const int mat = j >> 16, r = j & 65535;
        const int n = r >> 8, k = r & 255;
        v = XW[(size_t)mat * 65536 + k * 256 + n];
    } else {
        v = SW[idx - 983040];
    }
    ushort h, l; split2(v, h, l);
    Th[idx] = h; Tl[idx] = l;
}

// ---------------- MFMA GEMM core pieces (macros for reuse) -----------------
#define GEMM_DECLS                                                            \
    __shared__ ushort Ah[128 * KS], Al[128 * KS], Bh[128 * KS], Bl[128 * KS]; \
    const int tid = threadIdx.x;                                              \
    const int wave = tid >> 6, lane = tid & 63;                               \
    const int quad = lane >> 4, l16 = lane & 15;                              \
    const int wr = (wave >> 1) * 64, wc = (wave & 1) * 64;                    \
    f32x4 acc[4][4];                                                          \
    _Pragma("unroll") for (int i = 0; i < 4; i++)                             \
        _Pragma("unroll") for (int j = 0; j < 4; j++)                         \
            acc[i][j] = (f32x4){0.f, 0.f, 0.f, 0.f};

// Inline staging of pre-split ushort planes (R5 shape: load+write together,
// compiler pipelines). Thread owns LDS 16B chunks {tid, tid+256}; chunk ch ->
// row ch>>2, LINEAR dest slot; GLOBAL source k-chunk (ch&3)^((row>>1)&3)
// (involution). Dest start-banks cover all 8 groups -> conflict-free writes.
#define STAGE_US(dst, src, strideE, rowbase, k0e)                             \
    _Pragma("unroll") for (int cc = 0; cc < 2; cc++) {                        \
        const int ch_ = tid + cc * 256;                                       \
        const int r_ = ch_ >> 2;                                              \
        const int kq_ = (ch_ & 3) ^ ((r_ >> 1) & 3);                          \
        *(ushort8*)&(dst)[ch_ * 8] = *(const ushort8*)((src) +                \
            (size_t)((rowbase) + r_) * (strideE) + (k0e) + (kq_ << 3));       \
    }

// fp32 A staging (gemmf BLD half): load float4 x2, split, write 16B to the
// swizzled slot (verified byte-identical LDS image in R9/R10).
#define STAGE_F32(AhD, AlD, Aptr, kk)                                         \
    _Pragma("unroll") for (int cc = 0; cc < 2; cc++) {                        \
        const int ch = tid + cc * 256;                                        \
        const int r = ch >> 2, kq = ch & 3;                                   \
        const int wsl = (kq ^ ((r >> 1) & 3)) * 8;                            \
        const float* p = (Aptr) + (size_t)(m0 + r) * 256 + (kk) + kq * 8;     \
        const float4 v0 = *(const float4*)p;                                  \
        const float4 v1 = *(const float4*)(p + 4);                            \
        ushort8 h, l; ushort hh, ll;                                          \
        split2(v0.x, hh, ll); h[0] = hh; l[0] = ll;                           \
        split2(v0.y, hh, ll); h[1] = hh; l[1] = ll;                           \
        split2(v0.z, hh, ll); h[2] = hh; l[2] = ll;                           \
        split2(v0.w, hh, ll); h[3] = hh; l[3] = ll;                           \
        split2(v1.x, hh, ll); h[4] = hh; l[4] = ll;                           \
        split2(v1.y, hh, ll); h[5] = hh; l[5] = ll;                           \
        split2(v1.z, hh, ll); h[6] = hh; l[6] = ll;                           \
        split2(v1.w, hh, ll); h[7] = hh; l[7] = ll;                           \
        *(ushort8*)&(AhD)[r * KS + wsl] = h;                                  \
        *(ushort8*)&(AlD)[r * KS + wsl] = l;                                  \
    }

// Fragment reads XOR the same swizzle: slot = quad ^ ((l16>>1)&3).
#define GEMM_COMPUTE                                                          \
    {                                                                         \
        const int aswz = (l16 & 6) << 2;  /* ((l16>>1)&3)*8 */                \
        short8 afh[4], afl[4], bfh[4], bfl[4];                                \
        _Pragma("unroll") for (int i = 0; i < 4; i++) {                       \
            const int ro = (wr + i * 16 + l16) * KS + ((quad * 8) ^ aswz);    \
            afh[i] = *(const short8*)&Ah[ro];                                 \
            afl[i] = *(const short8*)&Al[ro];                                 \
        }                                                                     \
        _Pragma("unroll") for (int j = 0; j < 4; j++) {                       \
            const int no = (wc + j * 16 + l16) * KS + ((quad * 8) ^ aswz);    \
            bfh[j] = *(const short8*)&Bh[no];                                 \
            bfl[j] = *(const short8*)&Bl[no];                                 \
        }                                                                     \
        _Pragma("unroll") for (int i = 0; i < 4; i++)                         \
            _Pragma("unroll") for (int j = 0; j < 4; j++) {                   \
                acc[i][j] = __builtin_amdgcn_mfma_f32_16x16x32_bf16(          \
                    afh[i], bfh[j], acc[i][j], 0, 0, 0);                      \
                acc[i][j] = __builtin_amdgcn_mfma_f32_16x16x32_bf16(          \
                    afl[i], bfh[j], acc[i][j], 0, 0, 0);                      \
                acc[i][j] = __builtin_amdgcn_mfma_f32_16x16x32_bf16(          \
                    afh[i], bfl[j], acc[i][j], 0, 0, 0);                      \
            }                                                                 \
    }

// ---------- fused 3-matrix GEMM (Q,K,V or axial q,k,v): 1D grid nwg%8==0 ----
// XCD swizzle: lid = (bid%8)*(nwg/8) + bid/8; the 6 (mat,col) blocks sharing
// an A-tile get consecutive lids -> same XCD (group 6 divides nwg/8).
__global__ __launch_bounds__(256, 2) void gemm3_mfma(
    const ushort* __restrict__ AgH, const ushort* __restrict__ AgL,
    const ushort* __restrict__ Wth, const ushort* __restrict__ Wtl,
    const float* __restrict__ b0, const float* __restrict__ b1, const float* __restrict__ b2,
    float* __restrict__ O0, float* __restrict__ O1, float* __restrict__ O2)
{
    const int nq = gridDim.x >> 3;
    const int bid = blockIdx.x;
    const int lid = (bid & 7) * nq + (bid >> 3);
    const int m0 = (lid / 6) * 128;
    const int ymat = lid % 6;
    const int mat = ymat >> 1;
    const int col0 = (ymat & 1) * 128;
    const ushort* wth = Wth + (size_t)mat * 65536 + (size_t)col0 * 256;
    const ushort* wtl = Wtl + (size_t)mat * 65536 + (size_t)col0 * 256;
    GEMM_DECLS
    for (int k0 = 0; k0 < 256; k0 += 32) {
        STAGE_US(Ah, AgH, 256, m0, k0)
        STAGE_US(Al, AgL, 256, m0, k0)
        STAGE_US(Bh, wth, 256, 0, k0)
        STAGE_US(Bl, wtl, 256, 0, k0)
        __syncthreads();
        GEMM_COMPUTE
        __syncthreads();
    }
    const float* bias = (mat == 0) ? b0 : (mat == 1) ? b1 : b2;
    float* O = (mat == 0) ? O0 : (mat == 1) ? O1 : O2;
#pragma unroll
    for (int j = 0; j < 4; j++) {
        const int col = col0 + wc + j * 16 + l16;
        const float bj = bias[col];
#pragma unroll
        for (int i = 0; i < 4; i++) {
            const int rbase = m0 + wr + i * 16 + quad * 4;
#pragma unroll
            for (int r = 0; r < 4; r++)
                O[(size_t)(rbase + r) * 256 + col] = acc[i][j][r] + bj;
        }
    }
}

// ---------- out-projection GEMM with fused blend: 1D grid (M/128)*2 ---------
__global__ __launch_bounds__(256, 2) void gemmp_mfma(
    const ushort* __restrict__ AgH, const ushort* __restrict__ AgL,
    const ushort* __restrict__ Wth, const ushort* __restrict__ Wtl,
    const float* __restrict__ bias,
    float* __restrict__ Sout, int store_s,
    float* __restrict__ Blnd, const float* __restrict__ wts, int scale_idx, int blend_init,
    int row_off)
{
    const int nq = gridDim.x >> 3;
    const int bid = blockIdx.x;
    const int lid = (bid & 7) * nq + (bid >> 3);
    const int m0 = (lid >> 1) * 128;
    const int col0 = (lid & 1) * 128;
    const ushort* wth = Wth + (size_t)col0 * 256;
    const ushort* wtl = Wtl + (size_t)col0 * 256;
    GEMM_DECLS
    for (int k0 = 0; k0 < 256; k0 += 32) {
        STAGE_US(Ah, AgH, 256, m0, k0)
        STAGE_US(Al, AgL, 256, m0, k0)
        STAGE_US(Bh, wth, 256, 0, k0)
        STAGE_US(Bl, wtl, 256, 0, k0)
        __syncthreads();
        GEMM_COMPUTE
        __syncthreads();
    }
#pragma unroll
    for (int i = 0; i < 4; i++) {
        const int rbase = m0 + wr + i * 16 + quad * 4;
#pragma unroll
        for (int r = 0; r < 4; r++) {
            const size_t grow = (size_t)row_off + rbase + r;
            const float wt = wts[grow * 3 + scale_idx];
#pragma unroll
            for (int j = 0; j < 4; j++) {
                const int col = col0 + wc + j * 16 + l16;
                const float v = acc[i][j][r] + bias[col];
                if (store_s) Sout[grow * 256 + col] = v;
                float* bp = Blnd + grow * 256 + col;
                if (blend_init) *bp = wt * v;
                else            *bp = *bp + wt * v;
            }
        }
    }
}

// ---------- final squeeze: OUT = [UP | BL] @ sq_w^T + sq_b, K=512 -----------
__global__ __launch_bounds__(256, 2) void gemmf_mfma(
    const ushort* __restrict__ UPH, const ushort* __restrict__ UPL,
    const float* __restrict__ BLD,
    const ushort* __restrict__ Wth, const ushort* __restrict__ Wtl,
    const float* __restrict__ SQB, float* __restrict__ OUT)
{
    const int nq = gridDim.x >> 3;
    const int bid = blockIdx.x;
    const int lid = (bid & 7) * nq + (bid >> 3);
    const int m0 = (lid >> 1) * 128;
    const int col0 = (lid & 1) * 128;
    const ushort* wth = Wth + (size_t)col0 * 512;
    const ushort* wtl = Wtl + (size_t)col0 * 512;
    GEMM_DECLS
    for (int k0 = 0; k0 < 512; k0 += 32) {
        if (k0 < 256) {
            STAGE_US(Ah, UPH, 256, m0, k0)
            STAGE_US(Al, UPL, 256, m0, k0)
        } else {
            STAGE_F32(Ah, Al, BLD, (k0 & 255))
        }
        STAGE_US(Bh, wth, 512, 0, k0)
        STAGE_US(Bl, wtl, 512, 0, k0)
        __syncthreads();
        GEMM_COMPUTE
        __syncthreads();
    }
#pragma unroll
    for (int j = 0; j < 4; j++) {
        const int col = col0 + wc + j * 16 + l16;
        const float bj = SQB[col];
#pragma unroll
        for (int i = 0; i < 4; i++) {
            const int rbase = m0 + wr + i * 16 + quad * 4;
#pragma unroll
            for (int r = 0; r < 4; r++)
                OUT[(size_t)(rbase + r) * 256 + col] = acc[i][j][r] + bj;
        }
    }
}

// ----------------- windowed multi-head attention (per window) ---------------
template <int WS, int NH>
__global__ __launch_bounds__(256) void win_attn(
    const float* __restrict__ Q, const float* __restrict__ K,
    const float* __restrict__ V, ushort* __restrict__ CTXh, ushort* __restrict__ CTXl)
{
    constexpr int WIN = WS * WS;
    constexpr int NW = 64 / WS;
    constexpr int CW = NH * 32;
    __shared__ float qs[WIN][CW + 4], ks[WIN][CW + 4], vs[WIN][CW + 4];
    __shared__ float sc[NH][WIN][WIN + 1];
    const int tid = threadIdx.x;
    const int wid = blockIdx.x;
    const int b = wid / (NW * NW);
    const int rem = wid % (NW * NW);
    const int p = rem / NW, q = rem % NW;
    const int h0 = blockIdx.y * NH;

    for (int idx = tid; idx < WIN * CW; idx += 256) {
        const int i = idx / CW;
        const int cc = idx % CW;
        const int ti = i / WS, tj = i % WS;
        const size_t g = ((size_t)(b * 4096 + (p * WS + ti) * 64 + (q * WS + tj))) * 256 + h0 * 32 + cc;
        qs[i][cc] = Q[g]; ks[i][cc] = K[g]; vs[i][cc] = V[g];
    }
    __syncthreads();
    const float scale = 0.17677669529663687f;  // 1/sqrt(32)
    for (int idx = tid; idx < NH * WIN * WIN; idx += 256) {
        const int hl = idx / (WIN * WIN);
        const int r = idx % (WIN * WIN);
        const int i = r / WIN, j = r % WIN;
        const int co = hl * 32;
        float s = 0.f;
#pragma unroll
        for (int d = 0; d < 32; d++) s += qs[i][co + d] * ks[j][co + d];
        sc[hl][i][j] = s * scale;
    }
    __syncthreads();
    if (tid < NH * WIN) {
        const int hl = tid / WIN, i = tid % WIN;
        float mx = -3.4e38f;
        for (int j = 0; j < WIN; j++) mx = fmaxf(mx, sc[hl][i][j]);
        float sum = 0.f;
        for (int j = 0; j < WIN; j++) {
            float e = __expf(sc[hl][i][j] - mx);
            sc[hl][i][j] = e; sum += e;
        }
        const float inv = 1.f / sum;
        for (int j = 0; j < WIN; j++) sc[hl][i][j] *= inv;
    }
    __syncthreads();
    for (int idx = tid; idx < WIN * CW; idx += 256) {
        const int i = idx / CW;
        const int cc = idx % CW;
        const int hl = cc >> 5;
        float s = 0.f;
        for (int j = 0; j < WIN; j++) s += sc[hl][i][j] * vs[j][cc];
        const int ti = i / WS, tj = i % WS;
        const size_t g = ((size_t)(b * 4096 + (p * WS + ti) * 64 + (q * WS + tj))) * 256 + h0 * 32 + cc;
        ushort hh, ll; split2(s, hh, ll);
        CTXh[g] = hh; CTXl[g] = ll;
    }
}

// -------- edge conv phase 1 + fused x pre-split ----------------------------
__global__ __launch_bounds__(256) void edge_gemm9(
    const float* __restrict__ x, const float* __restrict__ ew, float* __restrict__ ytmp,
    ushort* __restrict__ Xh, ushort* __restrict__ Xl)
{
    __shared__ float wsm[2304];   // ew[c*9 + t]
    const int tid = threadIdx.x;
    for (int i = tid; i < 2304; i += 256) wsm[i] = ew[i];
    __syncthreads();
    const int wave = tid >> 6, lane = tid & 63;
    const int p = blockIdx.x * 4 + wave;            // pixel index 0..65535
    const float4 xv = *(const float4*)(x + (size_t)p * 256 + lane * 4);
    {
        ushort4 h4, l4;
        split2(xv.x, h4.x, l4.x); split2(xv.y, h4.y, l4.y);
        split2(xv.z, h4.z, l4.z); split2(xv.w, h4.w, l4.w);
        *(ushort4*)(Xh + (size_t)p * 256 + lane * 4) = h4;
        *(ushort4*)(Xl + (size_t)p * 256 + lane * 4) = l4;
    }
    float acc[9];
#pragma unroll
    for (int t = 0; t < 9; t++) acc[t] = 0.f;
    const float xs[4] = {xv.x, xv.y, xv.z, xv.w};
#pragma unroll
    for (int i = 0; i < 4; i++) {
        const int c = lane * 4 + i;
#pragma unroll
        for (int t = 0; t < 9; t++)
            acc[t] = fmaf(xs[i], wsm[c * 9 + t], acc[t]);
    }
#pragma unroll
    for (int t = 0; t < 9; t++) {
#pragma unroll
        for (int off = 1; off < 64; off <<= 1)
            acc[t] += __shfl_xor(acc[t], off);
    }
    if (lane < 9) {
        float v = acc[0];
        switch (lane) {
            case 1: v = acc[1]; break; case 2: v = acc[2]; break;
            case 3: v = acc[3]; break; case 4: v = acc[4]; break;
            case 5: v = acc[5]; break; case 6: v = acc[6]; break;
            case 7: v = acc[7]; break; case 8: v = acc[8]; break;
            default: break;
        }
        ytmp[(size_t)p * 9 + lane] = v;
    }
}

// -------- fused: edge_combine + box-avg + MLP + 3-way softmax ---------------
// Block = 4 image rows of one batch. LDS edge tile rows rblk-1..rblk+4
// (zero-filled outside image == reference's skip semantics).
__global__ __launch_bounds__(256) void edge_sel(
    const float* __restrict__ ytmp,
    const float* __restrict__ w1, const float* __restrict__ b1,
    const float* __restrict__ w2, const float* __restrict__ b2,
    float* __restrict__ wts)
{
    __shared__ float esm[6][65];
    const int tid = threadIdx.x;
    const int bid = blockIdx.x;          // 0..255
    const int b = bid >> 4;
    const int rblk = (bid & 15) * 4;
    for (int idx = tid; idx < 6 * 64; idx += 256) {
        const int er = idx >> 6, ew = idx & 63;
        const int hh = rblk + er - 1;
        float e = 0.f;
        if ((unsigned)hh <= 63u) {
            float s = 0.f;
#pragma unroll
            for (int kh = 0; kh < 3; kh++) {
                const int hy = hh + kh - 1;
                if ((unsigned)hy > 63u) continue;
#pragma unroll
                for (int kw = 0; kw < 3; kw++) {
                    const int wy = ew + kw - 1;
                    if ((unsigned)wy > 63u) continue;
                    s += ytmp[((size_t)b * 4096 + hy * 64 + wy) * 9 + kh * 3 + kw];
                }
            }
            e = fabsf(s);
        }
        esm[er][ew] = e;
    }
    __syncthreads();
    const int lh = tid >> 6, w = tid & 63;
    const int h = rblk + lh;
    float s = 0.f;
#pragma unroll
    for (int kh = 0; kh < 3; kh++) {
#pragma unroll
        for (int kw = 0; kw < 3; kw++) {
            const int ww = w + kw - 1;
            if ((unsigned)ww > 63u) continue;
            s += esm[lh + kh][ww];
        }
    }
    const float e = s / 9.f;
    float l0 = b2[0], l1 = b2[1], l2 = b2[2];
#pragma unroll
    for (int j = 0; j < 16; j++) {
        float hd = fmaxf(e * w1[j] + b1[j], 0.f);
        l0 += hd * w2[j * 3 + 0];
        l1 += hd * w2[j * 3 + 1];
        l2 += hd * w2[j * 3 + 2];
    }
    const float mx = fmaxf(l0, fmaxf(l1, l2));
    const float e0 = __expf(l0 - mx), e1 = __expf(l1 - mx), e2 = __expf(l2 - mx);
    const float inv = 1.f / (e0 + e1 + e2);
    const size_t gidx = (size_t)b * 4096 + h * 64 + w;
    wts[gidx * 3 + 0] = e0 * inv;
    wts[gidx * 3 + 1] = e1 * inv;
    wts[gidx * 3 + 2] = e2 * inv;
}

// ---------------------- DlightConv token pooling ----------------------------
__global__ __launch_bounds__(256) void dlight(
    const float* __restrict__ S1, const float* __restrict__ dlw,
    const float* __restrict__ dlb, ushort* __restrict__ XDLH, ushort* __restrict__ XDLL)
{
    __shared__ float xw[16][257];
    __shared__ float m[256];
    __shared__ float pr[16];
    __shared__ float pr2[16];
    const int wid = blockIdx.x;  // b*256 + p*16 + q
    const int b = wid >> 8, rem = wid & 255, p = rem >> 4, q = rem & 15;
    const int tid = threadIdx.x;  // channel
#pragma unroll
    for (int t = 0; t < 16; t++) {
        const int ti = t >> 2, tj = t & 3;
        xw[t][tid] = S1[((size_t)b * 4096 + (p * 4 + ti) * 64 + (q * 4 + tj)) * 256 + tid];
    }
    float mm = 0.f;
#pragma unroll
    for (int t = 0; t < 16; t++) mm += xw[t][tid];
    m[tid] = mm * (1.f / 16.f);
    __syncthreads();
    if (tid < 16) {
        float lg = dlb[tid];
        for (int c = 0; c < 256; c++) lg += m[c] * dlw[c * 16 + tid];
        pr[tid] = lg;
    }
    __syncthreads();
    if (tid < 16) {
        float mx = -3.4e38f;
        for (int j = 0; j < 16; j++) mx = fmaxf(mx, pr[j]);
        float sum = 0.f;
        for (int j = 0; j < 16; j++) sum += __expf(pr[j] - mx);
        pr2[tid] = __expf(pr[tid] - mx) / sum;
    }
    __syncthreads();
    float o = 0.f;
#pragma unroll
    for (int t = 0; t < 16; t++) o += xw[t][tid] * pr2[t];
    ushort hh, ll; split2(o, hh, ll);
    XDLH[(size_t)wid * 256 + tid] = hh;
    XDLL[(size_t)wid * 256 + tid] = ll;
}

// ----------------------------- axial attention ------------------------------
__global__ __launch_bounds__(256) void axial_row(
    const float* __restrict__ Q, const float* __restrict__ K, const float* __restrict__ V,
    const float* __restrict__ gsp, const float* __restrict__ gbp, float* __restrict__ XG)
{
    __shared__ float qs[16][257], ks[16][257], vs[16][257];
    __shared__ float sc[16][17];
    const int bid = blockIdx.x;
    const int b = bid >> 4, r = bid & 15;
    const int tid = threadIdx.x;
    const float gs = gsp[0], gb = gbp[0];
#pragma unroll
    for (int w = 0; w < 16; w++) {
        const size_t base = ((size_t)b * 256 + r * 16 + w) * 256 + tid;
        qs[w][tid] = Q[base]; ks[w][tid] = K[base]; vs[w][tid] = V[base];
    }
    __syncthreads();
    {
        const int w = tid >> 4, vv = tid & 15;
        float s = 0.f;
        for (int c = 0; c < 256; c++) s += qs[w][c] * ks[vv][c];
        const float d = (float)(w - vv);
        sc[w][vv] = s - (gs * d * d + gb);
    }
    __syncthreads();
    if (tid < 16) {
        float mx = -3.4e38f;
        for (int j = 0; j < 16; j++) mx = fmaxf(mx, sc[tid][j]);
        float sum = 0.f;
        for (int j = 0; j < 16; j++) {
            float e = __expf(sc[tid][j] - mx);
            sc[tid][j] = e; sum += e;
        }
        const float inv = 1.f / sum;
        for (int j = 0; j < 16; j++) sc[tid][j] *= inv;
    }
    __syncthreads();
#pragma unroll
    for (int w2 = 0; w2 < 16; w2++) {
        float o = 0.f;
#pragma unroll
        for (int k2 = 0; k2 < 16; k2++) o += sc[w2][k2] * vs[k2][tid];
        XG[((size_t)b * 256 + r * 16 + w2) * 256 + tid] = o;
    }
}

__global__ __launch_bounds__(256) void axial_col(
    const float* __restrict__ Q, const float* __restrict__ K, const float* __restrict__ V,
    const float* __restrict__ gsp, const float* __restrict__ gbp, float* __restrict__ XG)
{
    __shared__ float qs[16][257], ks[16][257], vs[16][257];
    __shared__ float sc[16][17];
    const int bid = blockIdx.x;
    const int b = bid >> 4, col = bid & 15;
    const int tid = threadIdx.x;
    const float gs = gsp[0], gb = gbp[0];
#pragma unroll
    for (int h = 0; h < 16; h++) {
        const size_t base = ((size_t)b * 256 + h * 16 + col) * 256 + tid;
        qs[h][tid] = Q[base]; ks[h][tid] = K[base]; vs[h][tid] = V[base];
    }
    __syncthreads();
    {
        const int r = tid >> 4, vv = tid & 15;
        float s = 0.f;
        for (int c = 0; c < 256; c++) s += qs[r][c] * ks[vv][c];
        const float d = (float)(r - vv);
        sc[r][vv] = s - (gs * d * d + gb);
    }
    __syncthreads();
    if (tid < 16) {
        float mx = -3.4e38f;
        for (int j = 0; j < 16; j++) mx = fmaxf(mx, sc[tid][j]);
        float sum = 0.f;
        for (int j = 0; j < 16; j++) {
            float e = __expf(sc[tid][j] - mx);
            sc[tid][j] = e; sum += e;
        }
        const float inv = 1.f / sum;
        for (int j = 0; j < 16; j++) sc[tid][j] *= inv;
    }
    __syncthreads();
#pragma unroll
    for (int r2 = 0; r2 < 16; r2++) {
        float o = 0.f;
#pragma unroll
        for (int k2 = 0; k2 < 16; k2++) o += sc[r2][k2] * vs[k2][tid];
        XG[((size_t)b * 256 + r2 * 16 + col) * 256 + tid] += o;
    }
}

// -------------------- bilinear upsample 16x16 -> 64x64 ----------------------
__global__ __launch_bounds__(256) void upsample(
    const float* __restrict__ XG, ushort* __restrict__ UPH, ushort* __restrict__ UPL)
{
    const unsigned idx = blockIdx.x * 256u + threadIdx.x;
    const int c = idx & 255;
    const unsigned t2 = idx >> 8;
    const int w = t2 & 63;
    const unsigned t3 = t2 >> 6;
    const int h = t3 & 63;
    const int b = t3 >> 6;
    const float rr = 15.f / 63.f;
    const float ph = h * rr, pw = w * rr;
    int h0 = (int)floorf(ph); float th = ph - (float)h0; int h1 = min(h0 + 1, 15);
    int w0 = (int)floorf(pw); float tw = pw - (float)w0; int w1 = min(w0 + 1, 15);
    const size_t bb = (size_t)b * 256;
    const float v00 = XG[((bb + h0 * 16 + w0)) * 256 + c];
    const float v10 = XG[((bb + h1 * 16 + w0)) * 256 + c];
    const float v01 = XG[((bb + h0 * 16 + w1)) * 256 + c];
    const float v11 = XG[((bb + h1 * 16 + w1)) * 256 + c];
    const float c0 = v00 * (1.f - th) + v10 * th;
    const float c1 = v01 * (1.f - th) + v11 * th;
    const float val = c0 * (1.f - tw) + c1 * tw;
    ushort hh, ll; split2(val, hh, ll);
    UPH[idx] = hh; UPL[idx] = ll;
}

// ---------------------------------------------------------------------------
extern "C" void kernel_launch(void* const* d_in, const int* in_sizes, int n_in,
                              void* d_out, int out_size, void* d_ws, size_t ws_size,
                              hipStream_t stream)
{
    const float* x      = (const float*)d_in[0];
    const float* attn_w = (const float*)d_in[1];
    const float* attn_b = (const float*)d_in[2];
    const float* edge_w = (const float*)d_in[3];
    const float* mlp_w1 = (const float*)d_in[4];
    const float* mlp_b1 = (const float*)d_in[5];
    const float* mlp_w2 = (const float*)d_in[6];
    const float* mlp_b2 = (const float*)d_in[7];
    const float* dl_w   = (const float*)d_in[8];
    const float* dl_b   = (const float*)d_in[9];
    const float* ax_w   = (const float*)d_in[10];
    const float* ax_b   = (const float*)d_in[11];
    const float* g_shift= (const float*)d_in[12];
    const float* g_bias = (const float*)d_in[13];
    const float* sq_w   = (const float*)d_in[14];
    const float* sq_b   = (const float*)d_in[15];
    float* out = (float*)d_out;

    float* ws = (float*)d_ws;
    const size_t MT = 65536;
    float* blend = ws;                       // 16,777,216 floats
    float* s1    = blend + MT * 256;         // 16,777,216
    float* scr   = s1 + MT * 256;            // 16,777,216 (ytmp / chunk QKV+ctx / up)
    float* chQ   = scr;
    float* chK   = chQ + (size_t)CHUNK_TOK * 256;
    float* chV   = chK + (size_t)CHUNK_TOK * 256;
    ushort* ctxh = (ushort*)(chV + (size_t)CHUNK_TOK * 256);  // 4,194,304 ushorts
    ushort* ctxl = ctxh + (size_t)CHUNK_TOK * 256;            // 4,194,304 ushorts
    ushort* uph  = (ushort*)scr;             // 16,777,216 ushorts (chunk bufs dead)
    ushort* upl  = uph + MT * 256;           // 16,777,216 ushorts
    float* ytmp  = scr;                      // 589,824 floats, dead before chQ use
    float* wts   = scr + MT * 256 + 65536;   // 196,608
    float* xdl   = wts + 196608;             // 1,048,576 floats region
    ushort* xdlh = (ushort*)xdl;             // 1,048,576 ushorts (2 MB)
    ushort* xdll = xdlh + 1048576;           // 1,048,576 ushorts (2 MB)
    float* axq   = xdl + 1048576;
    float* axk   = axq + 1048576;
    float* axv   = axk + 1048576;
    float* xg    = axv + 1048576;
    ushort* Wth = (ushort*)(xg + 1048576);
    ushort* Wtl = Wth + 1114112;
    // x hi/lo planes live in d_out (dead until gemmf writes it at the end)
    ushort* xh = (ushort*)out;               // 16,777,216 ushorts (32 MB)
    ushort* xl = xh + MT * 256;              // 16,777,216 ushorts (32 MB)

    // ---- pre-split all weights (one dispatch) -----------------------------
    split_w_all<<<(1114112 + 255) / 256, 256, 0, stream>>>(
        attn_w, ax_w, sq_w, Wth, Wtl);

    // ---- selector path: edge gemm (+x pre-split), fused combine+MLP -------
    edge_gemm9<<<16384, 256, 0, stream>>>(x, edge_w, ytmp, xh, xl);
    edge_sel<<<256, 256, 0, stream>>>(ytmp, mlp_w1, mlp_b1, mlp_w2, mlp_b2, wts);

    // ---- three window-attention scales: CHUNKS OUTER, SCALES INNER --------
    for (int ch = 0; ch < 16 / CHUNK_B; ch++) {
        const size_t toff = (size_t)ch * CHUNK_TOK;
        for (int i = 0; i < 3; i++) {
            const ushort* Wh = Wth + (size_t)i * 4 * 65536;
            const ushort* Wl = Wtl + (size_t)i * 4 * 65536;
            const float* c0 = attn_b + (size_t)(i * 4 + 0) * 256;
            const float* c1 = attn_b + (size_t)(i * 4 + 1) * 256;
            const float* c2 = attn_b + (size_t)(i * 4 + 2) * 256;
            const float* c3 = attn_b + (size_t)(i * 4 + 3) * 256;
            gemm3_mfma<<<CHUNK_TOK / 128 * 6, 256, 0, stream>>>(
                xh + toff * 256, xl + toff * 256, Wh, Wl, c0, c1, c2, chQ, chK, chV);
            if (i == 0)
                win_attn<2, 8><<<dim3(CHUNK_B * 32 * 32, 1), 256, 0, stream>>>(chQ, chK, chV, ctxh, ctxl);
            if (i == 1)
                win_attn<4, 4><<<dim3(CHUNK_B * 16 * 16, 2), 256, 0, stream>>>(chQ, chK, chV, ctxh, ctxl);
            if (i == 2)
                win_attn<8, 1><<<dim3(CHUNK_B * 8 * 8, 8), 256, 0, stream>>>(chQ, chK, chV, ctxh, ctxl);
            gemmp_mfma<<<CHUNK_TOK / 128 * 2, 256, 0, stream>>>(
                ctxh, ctxl, Wh + (size_t)3 * 65536, Wl + (size_t)3 * 65536, c3,
                s1, (i == 1) ? 1 : 0, blend, wts, i, (i == 0) ? 1 : 0, (int)toff);
        }
    }

    // ---- DlightConv pooling on s1 (emits pre-split xdl) -------------------
    dlight<<<4096, 256, 0, stream>>>(s1, dl_w, dl_b, xdlh, xdll);

    // ---- axial q,k,v projections (M = 4096) -------------------------------
    gemm3_mfma<<<4096 / 128 * 6, 256, 0, stream>>>(
        xdlh, xdll, Wth + (size_t)12 * 65536, Wtl + (size_t)12 * 65536,
        ax_b, ax_b + 256, ax_b + 512, axq, axk, axv);
    axial_row<<<256, 256, 0, stream>>>(axq, axk, axv, g_shift, g_bias, xg);
    axial_col<<<256, 256, 0, stream>>>(axq, axk, axv, g_shift, g_bias, xg);

    // ---- upsample 16x16 -> 64x64, pre-split, into reused scr region -------
    upsample<<<65536, 256, 0, stream>>>(xg, uph, upl);

    // ---- final squeeze GEMM (K=512) ---------------------------------------
    gemmf_mfma<<<1024, 256, 0, stream>>>(
        uph, upl, blend, Wth + (size_t)15 * 65536, Wtl + (size_t)15 * 65536, sq_b, out);
}